// Round 14
// baseline (52.642 us; speedup 1.0000x reference)
//
#include <hip/hip_runtime.h>
#include <hip/hip_bf16.h>

#define NROWS 8192
#define DIM   256
// zk stores z * SQ_SCALE, SQ_SCALE^2 = 10*log2(e) = 14.4269504089 -> MFMA
// yields 14.43*cos, so exp(sim) = 2^(mfma_out) = v_exp_f32(mfma_out).
#define SQ_SCALE 3.798282387f
#define LN2      0.69314718056f    // 10 / 14.4269504089

typedef __attribute__((ext_vector_type(8))) short short8;
typedef __attribute__((ext_vector_type(4))) float f32x4;

__device__ __forceinline__ float bfbits2f(unsigned short u) {
    unsigned int x = ((unsigned int)u) << 16;
    float f; __builtin_memcpy(&f, &x, 4); return f;
}
__device__ __forceinline__ unsigned short f2bf(float x) {
    __hip_bfloat16 h = __float2bfloat16(x);
    unsigned short u; __builtin_memcpy(&u, &h, 2); return u;
}
// Raw 2^x: single VOP1. Input range is [-14.5, 14.5] -> no denormal/overflow
// concerns, so OCML's guard sequence is pure waste.
__device__ __forceinline__ float exp2_raw(float x) {
    float r;
    asm("v_exp_f32 %0, %1" : "=v"(r) : "v"(x));
    return r;
}

// ---------------------------------------------------------------------------
// Kernel 1: L2-normalize 16 rows/block fp32 -> bf16*SQ_SCALE into the
// fragment-native K-major layout:
//   (row,d) -> (row>>4)*4096 + (d>>5)*512 + ((d>>3)&3)*128 + (row&15)*8 + (d&7)
// LDS-staged so zk stores are fully coalesced. Also: exact rounded self-dot
// sd[row]; blocks 0..64 zero se/ps/acc. (Unchanged — passing since round 11.)
// ---------------------------------------------------------------------------
__global__ __launch_bounds__(256)
void normalize_kernel(const float* __restrict__ latent,
                      unsigned short* __restrict__ zk,
                      float* __restrict__ sd_out,
                      float* __restrict__ zero_region,   // se_sum||ps_sum (16384 f)
                      float* __restrict__ acc) {
    __shared__ unsigned short tile[4096];     // 8 KB, fragment-ordered
    const int tid = threadIdx.x;
    const int r  = tid >> 4;                  // row within 16-row tile
    const int i  = tid & 15;                  // 16 threads per row
    const int row = blockIdx.x * 16 + r;

    if (blockIdx.x < 64) zero_region[blockIdx.x * 256 + tid] = 0.f;
    if (blockIdx.x == 64 && tid < 2) acc[tid] = 0.f;

    const float4* lp = (const float4*)(latent + (size_t)row * DIM + i * 16);
    const float4 v0 = lp[0], v1 = lp[1], v2 = lp[2], v3 = lp[3];
    float s = v0.x*v0.x + v0.y*v0.y + v0.z*v0.z + v0.w*v0.w
            + v1.x*v1.x + v1.y*v1.y + v1.z*v1.z + v1.w*v1.w
            + v2.x*v2.x + v2.y*v2.y + v2.z*v2.z + v2.w*v2.w
            + v3.x*v3.x + v3.y*v3.y + v3.z*v3.z + v3.w*v3.w;
    #pragma unroll
    for (int m = 1; m < 16; m <<= 1) s += __shfl_xor(s, m, 64);
    const float sc = rsqrtf(s) * SQ_SCALE;

    float f[16];
    f[0]=v0.x; f[1]=v0.y; f[2]=v0.z; f[3]=v0.w; f[4]=v1.x; f[5]=v1.y; f[6]=v1.z; f[7]=v1.w;
    f[8]=v2.x; f[9]=v2.y; f[10]=v2.z; f[11]=v2.w; f[12]=v3.x; f[13]=v3.y; f[14]=v3.z; f[15]=v3.w;
    float sd = 0.f;
    #pragma unroll
    for (int j = 0; j < 16; ++j) {
        const unsigned short u = f2bf(f[j] * sc);
        const float rr = bfbits2f(u);
        sd += rr * rr;
        const int d = i * 16 + j;
        tile[(d >> 5) * 512 + ((d >> 3) & 3) * 128 + r * 8 + (d & 7)] = u;
    }
    #pragma unroll
    for (int m = 1; m < 16; m <<= 1) sd += __shfl_xor(sd, m, 64);
    if (i == 0) sd_out[row] = sd;
    __syncthreads();

    ushort4* dst = (ushort4*)(zk + (size_t)blockIdx.x * 4096);
    const ushort4* srcl = (const ushort4*)tile;
    #pragma unroll
    for (int k = 0; k < 4; ++k) dst[tid + k * 256] = srcl[tid + k * 256];
}

// ---------------------------------------------------------------------------
// Kernel 2: SYMMETRIC fused sim reductions, wrap-around round-robin schedule.
// Panel i (64 rows) sweeps tiles j = (i+d) & 127 for d = 0..64 (i<64) or
// d = 0..63 (i>=64): each unordered panel pair covered exactly once.
// ROUND-14 CHANGE: 8 splits per panel (was 4) -> grid 1024 = 4 blocks/CU
// -> 4 waves/SIMD (VGPR 112 <= 128 permits it; grid was the occupancy cap).
// Everything else is byte-identical to the passing round-13 kernel.
// ---------------------------------------------------------------------------
__global__ __launch_bounds__(256, 2)
void ntxent_main(const unsigned short* __restrict__ zk,
                 const int* __restrict__ labels,
                 float* __restrict__ se_sum,
                 float* __restrict__ ps_sum) {
    __shared__ float rse[64], rps[64];
    const int tid  = threadIdx.x;
    const int wave = tid >> 6, lane = tid & 63;
    const int lrow = lane & 15, kgrp = lane >> 4;
    const int panel = blockIdx.x >> 3, s = blockIdx.x & 7;
    const int nt = (panel < 64) ? 65 : 64;         // tiles incl diagonal (d=0)
    const int dbeg = (s * nt) >> 3, dend = ((s + 1) * nt) >> 3;

    if (tid < 64) { rse[tid] = 0.f; rps[tid] = 0.f; }

    // --- A fragments: panel's 64 rows x K=256, contiguous 16B/lane ---
    short8 a[4][8];
    #pragma unroll
    for (int q = 0; q < 4; ++q) {
        const unsigned short* base = zk + (size_t)(panel * 4 + q) * 4096 + lane * 8;
        #pragma unroll
        for (int kk = 0; kk < 8; ++kk) a[q][kk] = *(const short8*)(base + kk * 512);
    }
    int labr[16];
    #pragma unroll
    for (int q = 0; q < 4; ++q)
        #pragma unroll
        for (int j = 0; j < 4; ++j)
            labr[q * 4 + j] = labels[panel * 64 + q * 16 + kgrp * 4 + j];

    float se[16], ps[16];
    #pragma unroll
    for (int i = 0; i < 16; ++i) { se[i] = 0.f; ps[i] = 0.f; }

    short8 b[8];
    {
        const int j0 = (panel + dbeg) & 127;
        const unsigned short* b0 = zk + (size_t)(j0 * 4 + wave) * 4096 + lane * 8;
        #pragma unroll
        for (int kk = 0; kk < 8; ++kk) b[kk] = *(const short8*)(b0 + kk * 512);
    }

    #pragma unroll 1
    for (int d = dbeg; d < dend; ++d) {
        const int j = (panel + d) & 127;
        const int labc = labels[j * 64 + wave * 16 + lrow];
        f32x4 c[4];
        #pragma unroll
        for (int q = 0; q < 4; ++q) c[q] = (f32x4){0.f, 0.f, 0.f, 0.f};
        #pragma unroll
        for (int kk = 0; kk < 8; ++kk) {
            c[0] = __builtin_amdgcn_mfma_f32_16x16x32_bf16(a[0][kk], b[kk], c[0], 0, 0, 0);
            c[1] = __builtin_amdgcn_mfma_f32_16x16x32_bf16(a[1][kk], b[kk], c[1], 0, 0, 0);
            c[2] = __builtin_amdgcn_mfma_f32_16x16x32_bf16(a[2][kk], b[kk], c[2], 0, 0, 0);
            c[3] = __builtin_amdgcn_mfma_f32_16x16x32_bf16(a[3][kk], b[kk], c[3], 0, 0, 0);
        }
        // grouped prefetch of next tile, round-10 form (no prefetch on last)
        if (d + 1 < dend) {
            const int jn = (panel + d + 1) & 127;
            const unsigned short* nb = zk + (size_t)(jn * 4 + wave) * 4096 + lane * 8;
            #pragma unroll
            for (int kk = 0; kk < 8; ++kk) b[kk] = *(const short8*)(nb + kk * 512);
        }
        // epilogue: row accums + scalar col partials (lane's 16 values all
        // belong to tile-col lrow; rows span the 4 kgrp groups).
        float sc_ = 0.f, pc_ = 0.f;
        #pragma unroll
        for (int q = 0; q < 4; ++q)
            #pragma unroll
            for (int jj = 0; jj < 4; ++jj) {
                const int i = q * 4 + jj;
                const float e  = exp2_raw(c[q][jj]);
                const float pm = (labc == labr[i]) ? c[q][jj] : 0.f;
                se[i] += e;  ps[i] += pm;
                sc_   += e;  pc_   += pm;
            }
        if (d != 0) {                              // off-diagonal: emit col sums
            sc_ += __shfl_xor(sc_, 16, 64); sc_ += __shfl_xor(sc_, 32, 64);
            pc_ += __shfl_xor(pc_, 16, 64); pc_ += __shfl_xor(pc_, 32, 64);
            if (kgrp == 0) {
                const int col = j * 64 + wave * 16 + lrow;
                atomicAdd(&se_sum[col], sc_);
                atomicAdd(&ps_sum[col], pc_);
            }
        }
    }

    // --- row-sum flush: reduce over 16 col-lanes, combine waves in LDS,
    //     one global atomic set ---
    #pragma unroll
    for (int i = 0; i < 16; ++i) {
        #pragma unroll
        for (int m = 1; m < 16; m <<= 1) {
            se[i] += __shfl_xor(se[i], m, 64);
            ps[i] += __shfl_xor(ps[i], m, 64);
        }
    }
    __syncthreads();                 // rse/rps zeroing complete
    if (lrow == 0) {
        #pragma unroll
        for (int i = 0; i < 16; ++i) {
            const int rl = (i >> 2) * 16 + kgrp * 4 + (i & 3);
            atomicAdd(&rse[rl], se[i]);
            atomicAdd(&rps[rl], ps[i]);
        }
    }
    __syncthreads();
    if (tid < 64) {
        atomicAdd(&se_sum[panel * 64 + tid], rse[tid]);
        atomicAdd(&ps_sum[panel * 64 + tid], rps[tid]);
    }
}

// ---------------------------------------------------------------------------
// Kernel 3: parallel finalize, 32 blocks x 256 thr, per-block LOCAL histogram.
// loss_r = log(max(se_r - exp2(sd_r), eps)) - LN2*(ps_r - sd_r)/n_pos.
// ---------------------------------------------------------------------------
__global__ __launch_bounds__(256)
void ntxent_final(const float* __restrict__ se_sum,
                  const float* __restrict__ ps_sum,
                  const float* __restrict__ sd,
                  const int* __restrict__ labels,
                  float* __restrict__ acc) {
    __shared__ int hist[128];
    __shared__ float rc[4], rh[4];
    const int tid = threadIdx.x;
    if (tid < 128) hist[tid] = 0;
    __syncthreads();
    for (int i = tid; i < NROWS; i += 256) atomicAdd(&hist[labels[i]], 1);
    __syncthreads();

    const int r = blockIdx.x * 256 + tid;
    const int n = hist[labels[r]] - 1;
    float contrib = 0.f, hp = 0.f;
    if (n > 0) {
        const float s   = sd[r];
        const float see = fmaxf(se_sum[r] - exp2f(s), 1e-6f);   // remove self
        contrib = __logf(see) - LN2 * (ps_sum[r] - s) / (float)n;
        hp = 1.0f;
    }
    #pragma unroll
    for (int m = 32; m; m >>= 1) {
        contrib += __shfl_xor(contrib, m, 64);
        hp      += __shfl_xor(hp, m, 64);
    }
    if ((tid & 63) == 0) { rc[tid >> 6] = contrib; rh[tid >> 6] = hp; }
    __syncthreads();
    if (tid == 0) {
        atomicAdd(&acc[0], rc[0] + rc[1] + rc[2] + rc[3]);
        atomicAdd(&acc[1], rh[0] + rh[1] + rh[2] + rh[3]);
    }
}

__global__ void finalize_kernel(const float* __restrict__ acc,
                                float* __restrict__ out) {
    out[0] = acc[0] / fmaxf(acc[1], 1.0f);
}

extern "C" void kernel_launch(void* const* d_in, const int* in_sizes, int n_in,
                              void* d_out, int out_size, void* d_ws, size_t ws_size,
                              hipStream_t stream) {
    const float* latent = (const float*)d_in[0];
    const int*   labels = (const int*)d_in[1];
    float* out = (float*)d_out;

    unsigned short* zk = (unsigned short*)d_ws;                       // 4 MB
    char* p = (char*)d_ws + (size_t)NROWS * DIM * sizeof(unsigned short);
    float* se_sum = (float*)p;                                        // 32 KB
    float* ps_sum = (float*)(p + 32768);                              // 32 KB
    float* sd     = (float*)(p + 65536);                              // 32 KB (fully overwritten)
    float* acc    = (float*)(p + 98304);                              // 8 B

    normalize_kernel<<<NROWS / 16, 256, 0, stream>>>(latent, zk, sd, se_sum, acc);
    ntxent_main<<<1024, 256, 0, stream>>>(zk, labels, se_sum, ps_sum);
    ntxent_final<<<NROWS / 256, 256, 0, stream>>>(se_sum, ps_sum, sd, labels, acc);
    finalize_kernel<<<1, 1, 0, stream>>>(acc, out);
}

// Round 15
// 49.035 us; speedup vs baseline: 1.0735x; 1.0735x over previous
//
#include <hip/hip_runtime.h>
#include <hip/hip_bf16.h>

#define NROWS 8192
#define DIM   256
// zk stores z * SQ_SCALE, SQ_SCALE^2 = 10*log2(e) = 14.4269504089 -> MFMA
// yields 14.43*cos, so exp(sim) = 2^(mfma_out) = v_exp_f32(mfma_out).
#define SQ_SCALE 3.798282387f
#define LN2      0.69314718056f    // 10 / 14.4269504089

typedef __attribute__((ext_vector_type(8))) short short8;
typedef __attribute__((ext_vector_type(4))) float f32x4;

__device__ __forceinline__ float bfbits2f(unsigned short u) {
    unsigned int x = ((unsigned int)u) << 16;
    float f; __builtin_memcpy(&f, &x, 4); return f;
}
__device__ __forceinline__ unsigned short f2bf(float x) {
    __hip_bfloat16 h = __float2bfloat16(x);
    unsigned short u; __builtin_memcpy(&u, &h, 2); return u;
}
// Raw 2^x: single VOP1. Input range is [-14.5, 14.5] -> no denormal/overflow
// concerns, so OCML's guard sequence is pure waste.
__device__ __forceinline__ float exp2_raw(float x) {
    float r;
    asm("v_exp_f32 %0, %1" : "=v"(r) : "v"(x));
    return r;
}

// ---------------------------------------------------------------------------
// Kernel 1: L2-normalize 16 rows/block fp32 -> bf16*SQ_SCALE into the
// fragment-native K-major layout:
//   (row,d) -> (row>>4)*4096 + (d>>5)*512 + ((d>>3)&3)*128 + (row&15)*8 + (d&7)
// LDS-staged so zk stores are fully coalesced. Also: exact rounded self-dot
// sd[row]; blocks 0..63 zero se/ps; block 64 zeros acc[0..3] (sums + ticket).
// ---------------------------------------------------------------------------
__global__ __launch_bounds__(256)
void normalize_kernel(const float* __restrict__ latent,
                      unsigned short* __restrict__ zk,
                      float* __restrict__ sd_out,
                      float* __restrict__ zero_region,   // se_sum||ps_sum (16384 f)
                      float* __restrict__ acc) {
    __shared__ unsigned short tile[4096];     // 8 KB, fragment-ordered
    const int tid = threadIdx.x;
    const int r  = tid >> 4;                  // row within 16-row tile
    const int i  = tid & 15;                  // 16 threads per row
    const int row = blockIdx.x * 16 + r;

    if (blockIdx.x < 64) zero_region[blockIdx.x * 256 + tid] = 0.f;
    if (blockIdx.x == 64 && tid < 4) acc[tid] = 0.f;   // sums + ticket

    const float4* lp = (const float4*)(latent + (size_t)row * DIM + i * 16);
    const float4 v0 = lp[0], v1 = lp[1], v2 = lp[2], v3 = lp[3];
    float s = v0.x*v0.x + v0.y*v0.y + v0.z*v0.z + v0.w*v0.w
            + v1.x*v1.x + v1.y*v1.y + v1.z*v1.z + v1.w*v1.w
            + v2.x*v2.x + v2.y*v2.y + v2.z*v2.z + v2.w*v2.w
            + v3.x*v3.x + v3.y*v3.y + v3.z*v3.z + v3.w*v3.w;
    #pragma unroll
    for (int m = 1; m < 16; m <<= 1) s += __shfl_xor(s, m, 64);
    const float sc = rsqrtf(s) * SQ_SCALE;

    float f[16];
    f[0]=v0.x; f[1]=v0.y; f[2]=v0.z; f[3]=v0.w; f[4]=v1.x; f[5]=v1.y; f[6]=v1.z; f[7]=v1.w;
    f[8]=v2.x; f[9]=v2.y; f[10]=v2.z; f[11]=v2.w; f[12]=v3.x; f[13]=v3.y; f[14]=v3.z; f[15]=v3.w;
    float sd = 0.f;
    #pragma unroll
    for (int j = 0; j < 16; ++j) {
        const unsigned short u = f2bf(f[j] * sc);
        const float rr = bfbits2f(u);
        sd += rr * rr;
        const int d = i * 16 + j;
        tile[(d >> 5) * 512 + ((d >> 3) & 3) * 128 + r * 8 + (d & 7)] = u;
    }
    #pragma unroll
    for (int m = 1; m < 16; m <<= 1) sd += __shfl_xor(sd, m, 64);
    if (i == 0) sd_out[row] = sd;
    __syncthreads();

    ushort4* dst = (ushort4*)(zk + (size_t)blockIdx.x * 4096);
    const ushort4* srcl = (const ushort4*)tile;
    #pragma unroll
    for (int k = 0; k < 4; ++k) dst[tid + k * 256] = srcl[tid + k * 256];
}

// ---------------------------------------------------------------------------
// Kernel 2: SYMMETRIC fused sim reductions, wrap-around round-robin schedule.
// Panel i (64 rows) sweeps tiles j = (i+d) & 127 for d = 0..64 (i<64) or
// d = 0..63 (i>=64): each unordered panel pair covered exactly once.
// 4 splits per panel -> grid 512 (round-13 config: measured optimum; 8 splits
// regressed +3us in round 14 -- per-block prologue dominates over occupancy).
// Per 64x64 tile: row sums -> register accums + LDS flush; col sums (d!=0)
// -> scalar accum + XOR-16/32 butterfly + one fire-and-forget atomic.
// Self terms removed exactly in the final pass via sd.
// ---------------------------------------------------------------------------
__global__ __launch_bounds__(256, 2)
void ntxent_main(const unsigned short* __restrict__ zk,
                 const int* __restrict__ labels,
                 float* __restrict__ se_sum,
                 float* __restrict__ ps_sum) {
    __shared__ float rse[64], rps[64];
    const int tid  = threadIdx.x;
    const int wave = tid >> 6, lane = tid & 63;
    const int lrow = lane & 15, kgrp = lane >> 4;
    const int panel = blockIdx.x >> 2, s = blockIdx.x & 3;
    const int nt = (panel < 64) ? 65 : 64;         // tiles incl diagonal (d=0)
    const int dbeg = (s * nt) >> 2, dend = ((s + 1) * nt) >> 2;

    if (tid < 64) { rse[tid] = 0.f; rps[tid] = 0.f; }

    // --- A fragments: panel's 64 rows x K=256, contiguous 16B/lane ---
    short8 a[4][8];
    #pragma unroll
    for (int q = 0; q < 4; ++q) {
        const unsigned short* base = zk + (size_t)(panel * 4 + q) * 4096 + lane * 8;
        #pragma unroll
        for (int kk = 0; kk < 8; ++kk) a[q][kk] = *(const short8*)(base + kk * 512);
    }
    int labr[16];
    #pragma unroll
    for (int q = 0; q < 4; ++q)
        #pragma unroll
        for (int j = 0; j < 4; ++j)
            labr[q * 4 + j] = labels[panel * 64 + q * 16 + kgrp * 4 + j];

    float se[16], ps[16];
    #pragma unroll
    for (int i = 0; i < 16; ++i) { se[i] = 0.f; ps[i] = 0.f; }

    short8 b[8];
    {
        const int j0 = (panel + dbeg) & 127;
        const unsigned short* b0 = zk + (size_t)(j0 * 4 + wave) * 4096 + lane * 8;
        #pragma unroll
        for (int kk = 0; kk < 8; ++kk) b[kk] = *(const short8*)(b0 + kk * 512);
    }

    #pragma unroll 1
    for (int d = dbeg; d < dend; ++d) {
        const int j = (panel + d) & 127;
        const int labc = labels[j * 64 + wave * 16 + lrow];
        f32x4 c[4];
        #pragma unroll
        for (int q = 0; q < 4; ++q) c[q] = (f32x4){0.f, 0.f, 0.f, 0.f};
        #pragma unroll
        for (int kk = 0; kk < 8; ++kk) {
            c[0] = __builtin_amdgcn_mfma_f32_16x16x32_bf16(a[0][kk], b[kk], c[0], 0, 0, 0);
            c[1] = __builtin_amdgcn_mfma_f32_16x16x32_bf16(a[1][kk], b[kk], c[1], 0, 0, 0);
            c[2] = __builtin_amdgcn_mfma_f32_16x16x32_bf16(a[2][kk], b[kk], c[2], 0, 0, 0);
            c[3] = __builtin_amdgcn_mfma_f32_16x16x32_bf16(a[3][kk], b[kk], c[3], 0, 0, 0);
        }
        // grouped prefetch of next tile (no prefetch on last)
        if (d + 1 < dend) {
            const int jn = (panel + d + 1) & 127;
            const unsigned short* nb = zk + (size_t)(jn * 4 + wave) * 4096 + lane * 8;
            #pragma unroll
            for (int kk = 0; kk < 8; ++kk) b[kk] = *(const short8*)(nb + kk * 512);
        }
        // epilogue: row accums + scalar col partials (lane's 16 values all
        // belong to tile-col lrow; rows span the 4 kgrp groups).
        float sc_ = 0.f, pc_ = 0.f;
        #pragma unroll
        for (int q = 0; q < 4; ++q)
            #pragma unroll
            for (int jj = 0; jj < 4; ++jj) {
                const int i = q * 4 + jj;
                const float e  = exp2_raw(c[q][jj]);
                const float pm = (labc == labr[i]) ? c[q][jj] : 0.f;
                se[i] += e;  ps[i] += pm;
                sc_   += e;  pc_   += pm;
            }
        if (d != 0) {                              // off-diagonal: emit col sums
            sc_ += __shfl_xor(sc_, 16, 64); sc_ += __shfl_xor(sc_, 32, 64);
            pc_ += __shfl_xor(pc_, 16, 64); pc_ += __shfl_xor(pc_, 32, 64);
            if (kgrp == 0) {
                const int col = j * 64 + wave * 16 + lrow;
                atomicAdd(&se_sum[col], sc_);
                atomicAdd(&ps_sum[col], pc_);
            }
        }
    }

    // --- row-sum flush: reduce over 16 col-lanes, combine waves in LDS,
    //     one global atomic set ---
    #pragma unroll
    for (int i = 0; i < 16; ++i) {
        #pragma unroll
        for (int m = 1; m < 16; m <<= 1) {
            se[i] += __shfl_xor(se[i], m, 64);
            ps[i] += __shfl_xor(ps[i], m, 64);
        }
    }
    __syncthreads();                 // rse/rps zeroing complete
    if (lrow == 0) {
        #pragma unroll
        for (int i = 0; i < 16; ++i) {
            const int rl = (i >> 2) * 16 + kgrp * 4 + (i & 3);
            atomicAdd(&rse[rl], se[i]);
            atomicAdd(&rps[rl], ps[i]);
        }
    }
    __syncthreads();
    if (tid < 64) {
        atomicAdd(&se_sum[panel * 64 + tid], rse[tid]);
        atomicAdd(&ps_sum[panel * 64 + tid], rps[tid]);
    }
}

// ---------------------------------------------------------------------------
// Kernel 3: parallel finalize, 32 blocks x 256 thr, per-block LOCAL histogram.
// loss_r = log(max(se_r - exp2(sd_r), eps)) - LN2*(ps_r - sd_r)/n_pos.
// Last block (device-scope ticket) computes the final quotient -> no separate
// single-thread finalize dispatch. Ticket (acc[2]) zeroed by normalize.
// ---------------------------------------------------------------------------
__global__ __launch_bounds__(256)
void ntxent_final(const float* __restrict__ se_sum,
                  const float* __restrict__ ps_sum,
                  const float* __restrict__ sd,
                  const int* __restrict__ labels,
                  float* __restrict__ acc,
                  float* __restrict__ out) {
    __shared__ int hist[128];
    __shared__ float rc[4], rh[4];
    const int tid = threadIdx.x;
    if (tid < 128) hist[tid] = 0;
    __syncthreads();
    for (int i = tid; i < NROWS; i += 256) atomicAdd(&hist[labels[i]], 1);
    __syncthreads();

    const int r = blockIdx.x * 256 + tid;
    const int n = hist[labels[r]] - 1;
    float contrib = 0.f, hp = 0.f;
    if (n > 0) {
        const float s   = sd[r];
        const float see = fmaxf(se_sum[r] - exp2f(s), 1e-6f);   // remove self
        contrib = __logf(see) - LN2 * (ps_sum[r] - s) / (float)n;
        hp = 1.0f;
    }
    #pragma unroll
    for (int m = 32; m; m >>= 1) {
        contrib += __shfl_xor(contrib, m, 64);
        hp      += __shfl_xor(hp, m, 64);
    }
    if ((tid & 63) == 0) { rc[tid >> 6] = contrib; rh[tid >> 6] = hp; }
    __syncthreads();
    if (tid == 0) {
        atomicAdd(&acc[0], rc[0] + rc[1] + rc[2] + rc[3]);
        atomicAdd(&acc[1], rh[0] + rh[1] + rh[2] + rh[3]);
        __threadfence();                                   // publish sums
        unsigned int* ticket = (unsigned int*)(acc + 2);
        if (atomicAdd(ticket, 1u) == 31u) {                // last block
            const float c = atomicAdd(&acc[0], 0.f);       // coherent reads
            const float h = atomicAdd(&acc[1], 0.f);
            out[0] = c / fmaxf(h, 1.0f);
        }
    }
}

extern "C" void kernel_launch(void* const* d_in, const int* in_sizes, int n_in,
                              void* d_out, int out_size, void* d_ws, size_t ws_size,
                              hipStream_t stream) {
    const float* latent = (const float*)d_in[0];
    const int*   labels = (const int*)d_in[1];
    float* out = (float*)d_out;

    unsigned short* zk = (unsigned short*)d_ws;                       // 4 MB
    char* p = (char*)d_ws + (size_t)NROWS * DIM * sizeof(unsigned short);
    float* se_sum = (float*)p;                                        // 32 KB
    float* ps_sum = (float*)(p + 32768);                              // 32 KB
    float* sd     = (float*)(p + 65536);                              // 32 KB (fully overwritten)
    float* acc    = (float*)(p + 98304);                              // 16 B (sums + ticket)

    normalize_kernel<<<NROWS / 16, 256, 0, stream>>>(latent, zk, sd, se_sum, acc);
    ntxent_main<<<512, 256, 0, stream>>>(zk, labels, se_sum, ps_sum);
    ntxent_final<<<NROWS / 256, 256, 0, stream>>>(se_sum, ps_sum, sd, labels, acc, out);
}

// Round 17
// 48.925 us; speedup vs baseline: 1.0760x; 1.0023x over previous
//
#include <hip/hip_runtime.h>
#include <hip/hip_bf16.h>

#define NROWS 8192
#define DIM   256
// zk stores z * SQ_SCALE, SQ_SCALE^2 = 10*log2(e) = 14.4269504089 -> MFMA
// yields 14.43*cos, so exp(sim) = 2^(mfma_out) = v_exp_f32(mfma_out).
#define SQ_SCALE 3.798282387f
#define LN2      0.69314718056f    // 10 / 14.4269504089

typedef __attribute__((ext_vector_type(8))) short short8;
typedef __attribute__((ext_vector_type(4))) float f32x4;

__device__ __forceinline__ float bfbits2f(unsigned short u) {
    unsigned int x = ((unsigned int)u) << 16;
    float f; __builtin_memcpy(&f, &x, 4); return f;
}
__device__ __forceinline__ unsigned short f2bf(float x) {
    __hip_bfloat16 h = __float2bfloat16(x);
    unsigned short u; __builtin_memcpy(&u, &h, 2); return u;
}
// Raw 2^x: single VOP1. Input range is [-14.5, 14.5] -> no denormal/overflow
// concerns, so OCML's guard sequence is pure waste.
__device__ __forceinline__ float exp2_raw(float x) {
    float r;
    asm("v_exp_f32 %0, %1" : "=v"(r) : "v"(x));
    return r;
}

// ---------------------------------------------------------------------------
// Kernel 1: L2-normalize 16 rows/block fp32 -> bf16*SQ_SCALE into the
// fragment-native K-major layout:
//   (row,d) -> (row>>4)*4096 + (d>>5)*512 + ((d>>3)&3)*128 + (row&15)*8 + (d&7)
// LDS-staged so zk stores are fully coalesced. Also: exact rounded self-dot
// sd[row]; blocks 0..63 zero se/ps; block 64 zeros acc[0..3] (sums + ticket).
// ---------------------------------------------------------------------------
__global__ __launch_bounds__(256)
void normalize_kernel(const float* __restrict__ latent,
                      unsigned short* __restrict__ zk,
                      float* __restrict__ sd_out,
                      float* __restrict__ zero_region,   // se_sum||ps_sum (16384 f)
                      float* __restrict__ acc) {
    __shared__ unsigned short tile[4096];     // 8 KB, fragment-ordered
    const int tid = threadIdx.x;
    const int r  = tid >> 4;                  // row within 16-row tile
    const int i  = tid & 15;                  // 16 threads per row
    const int row = blockIdx.x * 16 + r;

    if (blockIdx.x < 64) zero_region[blockIdx.x * 256 + tid] = 0.f;
    if (blockIdx.x == 64 && tid < 4) acc[tid] = 0.f;   // sums + ticket

    const float4* lp = (const float4*)(latent + (size_t)row * DIM + i * 16);
    const float4 v0 = lp[0], v1 = lp[1], v2 = lp[2], v3 = lp[3];
    float s = v0.x*v0.x + v0.y*v0.y + v0.z*v0.z + v0.w*v0.w
            + v1.x*v1.x + v1.y*v1.y + v1.z*v1.z + v1.w*v1.w
            + v2.x*v2.x + v2.y*v2.y + v2.z*v2.z + v2.w*v2.w
            + v3.x*v3.x + v3.y*v3.y + v3.z*v3.z + v3.w*v3.w;
    #pragma unroll
    for (int m = 1; m < 16; m <<= 1) s += __shfl_xor(s, m, 64);
    const float sc = rsqrtf(s) * SQ_SCALE;

    float f[16];
    f[0]=v0.x; f[1]=v0.y; f[2]=v0.z; f[3]=v0.w; f[4]=v1.x; f[5]=v1.y; f[6]=v1.z; f[7]=v1.w;
    f[8]=v2.x; f[9]=v2.y; f[10]=v2.z; f[11]=v2.w; f[12]=v3.x; f[13]=v3.y; f[14]=v3.z; f[15]=v3.w;
    float sd = 0.f;
    #pragma unroll
    for (int j = 0; j < 16; ++j) {
        const unsigned short u = f2bf(f[j] * sc);
        const float rr = bfbits2f(u);
        sd += rr * rr;
        const int d = i * 16 + j;
        tile[(d >> 5) * 512 + ((d >> 3) & 3) * 128 + r * 8 + (d & 7)] = u;
    }
    #pragma unroll
    for (int m = 1; m < 16; m <<= 1) sd += __shfl_xor(sd, m, 64);
    if (i == 0) sd_out[row] = sd;
    __syncthreads();

    ushort4* dst = (ushort4*)(zk + (size_t)blockIdx.x * 4096);
    const ushort4* srcl = (const ushort4*)tile;
    #pragma unroll
    for (int k = 0; k < 4; ++k) dst[tid + k * 256] = srcl[tid + k * 256];
}

// ---------------------------------------------------------------------------
// Kernel 2: SYMMETRIC fused sim reductions, wrap-around round-robin schedule.
// Panel i (64 rows) sweeps tiles j = (i+d) & 127 for d = 0..64 (i<64) or
// d = 0..63 (i>=64): each unordered panel pair covered exactly once.
// 4 splits per panel -> grid 512 (measured optimum; 8 splits regressed).
// Per 64x64 tile: row sums -> register accums + LDS flush; col sums (d!=0)
// -> scalar accum + XOR-16/32 butterfly + one fire-and-forget atomic.
// Single b-buffer, grouped prefetch after the MFMA chain (measured best
// schedule: interleaved [r11] and ping-pong [r16] variants both worse/broken).
// Self terms removed exactly in the final pass via sd.
// ---------------------------------------------------------------------------
__global__ __launch_bounds__(256, 2)
void ntxent_main(const unsigned short* __restrict__ zk,
                 const int* __restrict__ labels,
                 float* __restrict__ se_sum,
                 float* __restrict__ ps_sum) {
    __shared__ float rse[64], rps[64];
    const int tid  = threadIdx.x;
    const int wave = tid >> 6, lane = tid & 63;
    const int lrow = lane & 15, kgrp = lane >> 4;
    const int panel = blockIdx.x >> 2, s = blockIdx.x & 3;
    const int nt = (panel < 64) ? 65 : 64;         // tiles incl diagonal (d=0)
    const int dbeg = (s * nt) >> 2, dend = ((s + 1) * nt) >> 2;

    if (tid < 64) { rse[tid] = 0.f; rps[tid] = 0.f; }

    // --- A fragments: panel's 64 rows x K=256, contiguous 16B/lane ---
    short8 a[4][8];
    #pragma unroll
    for (int q = 0; q < 4; ++q) {
        const unsigned short* base = zk + (size_t)(panel * 4 + q) * 4096 + lane * 8;
        #pragma unroll
        for (int kk = 0; kk < 8; ++kk) a[q][kk] = *(const short8*)(base + kk * 512);
    }
    int labr[16];
    #pragma unroll
    for (int q = 0; q < 4; ++q)
        #pragma unroll
        for (int j = 0; j < 4; ++j)
            labr[q * 4 + j] = labels[panel * 64 + q * 16 + kgrp * 4 + j];

    float se[16], ps[16];
    #pragma unroll
    for (int i = 0; i < 16; ++i) { se[i] = 0.f; ps[i] = 0.f; }

    short8 b[8];
    {
        const int j0 = (panel + dbeg) & 127;
        const unsigned short* b0 = zk + (size_t)(j0 * 4 + wave) * 4096 + lane * 8;
        #pragma unroll
        for (int kk = 0; kk < 8; ++kk) b[kk] = *(const short8*)(b0 + kk * 512);
    }

    #pragma unroll 1
    for (int d = dbeg; d < dend; ++d) {
        const int j = (panel + d) & 127;
        const int labc = labels[j * 64 + wave * 16 + lrow];
        f32x4 c[4];
        #pragma unroll
        for (int q = 0; q < 4; ++q) c[q] = (f32x4){0.f, 0.f, 0.f, 0.f};
        #pragma unroll
        for (int kk = 0; kk < 8; ++kk) {
            c[0] = __builtin_amdgcn_mfma_f32_16x16x32_bf16(a[0][kk], b[kk], c[0], 0, 0, 0);
            c[1] = __builtin_amdgcn_mfma_f32_16x16x32_bf16(a[1][kk], b[kk], c[1], 0, 0, 0);
            c[2] = __builtin_amdgcn_mfma_f32_16x16x32_bf16(a[2][kk], b[kk], c[2], 0, 0, 0);
            c[3] = __builtin_amdgcn_mfma_f32_16x16x32_bf16(a[3][kk], b[kk], c[3], 0, 0, 0);
        }
        // grouped prefetch of next tile (no prefetch on last)
        if (d + 1 < dend) {
            const int jn = (panel + d + 1) & 127;
            const unsigned short* nb = zk + (size_t)(jn * 4 + wave) * 4096 + lane * 8;
            #pragma unroll
            for (int kk = 0; kk < 8; ++kk) b[kk] = *(const short8*)(nb + kk * 512);
        }
        // epilogue: row accums + scalar col partials (lane's 16 values all
        // belong to tile-col lrow; rows span the 4 kgrp groups).
        float sc_ = 0.f, pc_ = 0.f;
        #pragma unroll
        for (int q = 0; q < 4; ++q)
            #pragma unroll
            for (int jj = 0; jj < 4; ++jj) {
                const int i = q * 4 + jj;
                const float e  = exp2_raw(c[q][jj]);
                const float pm = (labc == labr[i]) ? c[q][jj] : 0.f;
                se[i] += e;  ps[i] += pm;
                sc_   += e;  pc_   += pm;
            }
        if (d != 0) {                              // off-diagonal: emit col sums
            sc_ += __shfl_xor(sc_, 16, 64); sc_ += __shfl_xor(sc_, 32, 64);
            pc_ += __shfl_xor(pc_, 16, 64); pc_ += __shfl_xor(pc_, 32, 64);
            if (kgrp == 0) {
                const int col = j * 64 + wave * 16 + lrow;
                atomicAdd(&se_sum[col], sc_);
                atomicAdd(&ps_sum[col], pc_);
            }
        }
    }

    // --- row-sum flush: reduce over 16 col-lanes, combine waves in LDS,
    //     one global atomic set ---
    #pragma unroll
    for (int i = 0; i < 16; ++i) {
        #pragma unroll
        for (int m = 1; m < 16; m <<= 1) {
            se[i] += __shfl_xor(se[i], m, 64);
            ps[i] += __shfl_xor(ps[i], m, 64);
        }
    }
    __syncthreads();                 // rse/rps zeroing complete
    if (lrow == 0) {
        #pragma unroll
        for (int i = 0; i < 16; ++i) {
            const int rl = (i >> 2) * 16 + kgrp * 4 + (i & 3);
            atomicAdd(&rse[rl], se[i]);
            atomicAdd(&rps[rl], ps[i]);
        }
    }
    __syncthreads();
    if (tid < 64) {
        atomicAdd(&se_sum[panel * 64 + tid], rse[tid]);
        atomicAdd(&ps_sum[panel * 64 + tid], rps[tid]);
    }
}

// ---------------------------------------------------------------------------
// Kernel 3: parallel finalize, 32 blocks x 256 thr, per-block LOCAL histogram.
// loss_r = log(max(se_r - exp2(sd_r), eps)) - LN2*(ps_r - sd_r)/n_pos.
// Last block (device-scope ticket) computes the final quotient.
// ---------------------------------------------------------------------------
__global__ __launch_bounds__(256)
void ntxent_final(const float* __restrict__ se_sum,
                  const float* __restrict__ ps_sum,
                  const float* __restrict__ sd,
                  const int* __restrict__ labels,
                  float* __restrict__ acc,
                  float* __restrict__ out) {
    __shared__ int hist[128];
    __shared__ float rc[4], rh[4];
    const int tid = threadIdx.x;
    if (tid < 128) hist[tid] = 0;
    __syncthreads();
    for (int i = tid; i < NROWS; i += 256) atomicAdd(&hist[labels[i]], 1);
    __syncthreads();

    const int r = blockIdx.x * 256 + tid;
    const int n = hist[labels[r]] - 1;
    float contrib = 0.f, hp = 0.f;
    if (n > 0) {
        const float s   = sd[r];
        const float see = fmaxf(se_sum[r] - exp2f(s), 1e-6f);   // remove self
        contrib = __logf(see) - LN2 * (ps_sum[r] - s) / (float)n;
        hp = 1.0f;
    }
    #pragma unroll
    for (int m = 32; m; m >>= 1) {
        contrib += __shfl_xor(contrib, m, 64);
        hp      += __shfl_xor(hp, m, 64);
    }
    if ((tid & 63) == 0) { rc[tid >> 6] = contrib; rh[tid >> 6] = hp; }
    __syncthreads();
    if (tid == 0) {
        atomicAdd(&acc[0], rc[0] + rc[1] + rc[2] + rc[3]);
        atomicAdd(&acc[1], rh[0] + rh[1] + rh[2] + rh[3]);
        __threadfence();                                   // publish sums
        unsigned int* ticket = (unsigned int*)(acc + 2);
        if (atomicAdd(ticket, 1u) == 31u) {                // last block
            const float c = atomicAdd(&acc[0], 0.f);       // coherent reads
            const float h = atomicAdd(&acc[1], 0.f);
            out[0] = c / fmaxf(h, 1.0f);
        }
    }
}

extern "C" void kernel_launch(void* const* d_in, const int* in_sizes, int n_in,
                              void* d_out, int out_size, void* d_ws, size_t ws_size,
                              hipStream_t stream) {
    const float* latent = (const float*)d_in[0];
    const int*   labels = (const int*)d_in[1];
    float* out = (float*)d_out;

    unsigned short* zk = (unsigned short*)d_ws;                       // 4 MB
    char* p = (char*)d_ws + (size_t)NROWS * DIM * sizeof(unsigned short);
    float* se_sum = (float*)p;                                        // 32 KB
    float* ps_sum = (float*)(p + 32768);                              // 32 KB
    float* sd     = (float*)(p + 65536);                              // 32 KB (fully overwritten)
    float* acc    = (float*)(p + 98304);                              // 16 B (sums + ticket)

    normalize_kernel<<<NROWS / 16, 256, 0, stream>>>(latent, zk, sd, se_sum, acc);
    ntxent_main<<<512, 256, 0, stream>>>(zk, labels, se_sum, ps_sum);
    ntxent_final<<<NROWS / 256, 256, 0, stream>>>(se_sum, ps_sum, sd, labels, acc, out);
}